// Round 3
// baseline (18.924 us; speedup 1.0000x reference)
//
#include <hip/hip_runtime.h>

// Problem constants (from reference): B=8, K=8, H=256, N=56564 (derived at launch).
#define K_PTS 8
#define HID   256
#define BATCH 8
#define GPB   64      // blocks per batch for the argmin pass
#define BLK   256

// ---------------------------------------------------------------------------
// Kernel 1: per (batch, gaussian k) argmin over N of squared distance.
// Packed (dist2_bits << 32) | idx: for non-negative floats the bit pattern is
// monotone in value, and min on the packed value breaks ties toward the
// SMALLER index — exactly jnp.argmax's first-occurrence semantics.
// ---------------------------------------------------------------------------
__global__ void __launch_bounds__(BLK)
argmin_kernel(const float* __restrict__ pos,
              const float* __restrict__ mean,
              unsigned long long* __restrict__ best,   // [BATCH][K_PTS]
              int N) {
    const int b = blockIdx.x / GPB;
    const int g = blockIdx.x % GPB;
    const int t = threadIdx.x;

    float mx[K_PTS], my[K_PTS], mz[K_PTS];
#pragma unroll
    for (int k = 0; k < K_PTS; ++k) {
        mx[k] = mean[k * 3 + 0];
        my[k] = mean[k * 3 + 1];
        mz[k] = mean[k * 3 + 2];
    }

    float bv[K_PTS];
    int   bi[K_PTS];
#pragma unroll
    for (int k = 0; k < K_PTS; ++k) { bv[k] = 3.4e38f; bi[k] = 0; }

    const float* posb = pos + (size_t)b * N * 3;
    for (int n = g * BLK + t; n < N; n += GPB * BLK) {
        const float px = posb[n * 3 + 0];
        const float py = posb[n * 3 + 1];
        const float pz = posb[n * 3 + 2];
#pragma unroll
        for (int k = 0; k < K_PTS; ++k) {
            const float dx = px - mx[k];
            const float dy = py - my[k];
            const float dz = pz - mz[k];
            const float d2 = dx * dx + dy * dy + dz * dz;
            // strict < keeps the earlier (smaller) n within this thread
            if (d2 < bv[k]) { bv[k] = d2; bi[k] = n; }
        }
    }

    __shared__ unsigned long long red[K_PTS][BLK];   // 16 KiB
#pragma unroll
    for (int k = 0; k < K_PTS; ++k)
        red[k][t] = ((unsigned long long)__float_as_uint(bv[k]) << 32)
                  | (unsigned int)bi[k];
    __syncthreads();

    for (int s = BLK / 2; s > 0; s >>= 1) {
        if (t < s) {
#pragma unroll
            for (int k = 0; k < K_PTS; ++k) {
                const unsigned long long o = red[k][t + s];
                if (o < red[k][t]) red[k][t] = o;
            }
        }
        __syncthreads();
    }

    if (t < K_PTS)
        atomicMin(&best[b * K_PTS + t], red[t][0]);
}

// ---------------------------------------------------------------------------
// Kernel 2: dedup the K indices per batch (clip(sum one_hot,0,1) == union),
// then out[b,h] = bias[h] + sum_u x[b,n_u] * W[n_u,h].
// ---------------------------------------------------------------------------
__global__ void __launch_bounds__(HID)
gather_kernel(const float* __restrict__ x,
              const float* __restrict__ weight,   // [N][HID]
              const float* __restrict__ bias,     // [HID]
              const unsigned long long* __restrict__ best,
              float* __restrict__ out,            // [BATCH][HID]
              int N) {
    const int b = blockIdx.x;
    const int t = threadIdx.x;

    __shared__ int sel[K_PTS];
    __shared__ int nsel;
    if (t == 0) {
        int idxs[K_PTS];
#pragma unroll
        for (int k = 0; k < K_PTS; ++k)
            idxs[k] = (int)(best[b * K_PTS + k] & 0xFFFFFFFFull);
        int u = 0;
#pragma unroll
        for (int k = 0; k < K_PTS; ++k) {
            bool dup = false;
#pragma unroll
            for (int j = 0; j < K_PTS; ++j)
                dup |= (j < k) && (idxs[j] == idxs[k]);
            if (!dup) sel[u++] = idxs[k];
        }
        nsel = u;
    }
    __syncthreads();

    float acc = bias[t];
    const int u = nsel;
    for (int i = 0; i < u; ++i) {
        const int n = sel[i];
        acc += x[(size_t)b * N + n] * weight[(size_t)n * HID + t];
    }
    out[b * HID + t] = acc;
}

extern "C" void kernel_launch(void* const* d_in, const int* in_sizes, int n_in,
                              void* d_out, int out_size, void* d_ws, size_t ws_size,
                              hipStream_t stream) {
    const float* x      = (const float*)d_in[0];   // [B, N]
    const float* pos    = (const float*)d_in[1];   // [B, N, 3]
    const float* mean   = (const float*)d_in[2];   // [K, 3]
    const float* weight = (const float*)d_in[3];   // [1, N, H]
    const float* bias   = (const float*)d_in[4];   // [1, H]
    float* out = (float*)d_out;

    const int N = in_sizes[0] / BATCH;

    unsigned long long* best = (unsigned long long*)d_ws;

    // init the 64 packed-min slots to all-ones (== +max)
    hipMemsetAsync(d_ws, 0xFF, BATCH * K_PTS * sizeof(unsigned long long), stream);

    argmin_kernel<<<BATCH * GPB, BLK, 0, stream>>>(pos, mean, best, N);
    gather_kernel<<<BATCH, HID, 0, stream>>>(x, weight, bias, best, out, N);
}

// Round 4
// 12.830 us; speedup vs baseline: 1.4750x; 1.4750x over previous
//
#include <hip/hip_runtime.h>

// B=8, K=8, H=256; N derived at launch (56564).
#define K_PTS 8
#define HID   256
#define BATCH 8
#define GPB   64      // blocks per batch for the argmin pass
#define BLK   256     // threads per block (4 waves)

// Packed (dist2_bits << 32) | idx: bit pattern of non-negative f32 is
// monotone in value; min on the packed value breaks ties toward the smaller
// index — matching jnp.argmax first-occurrence semantics.

// ---------------------------------------------------------------------------
// Kernel 1: per-(batch, block) partial argmin over its slice of N, for all K
// gaussians. Each block writes K plain u64 results to ws — no init, no atomics.
// ws layout: partial[(b*K + k)*GPB + g]
// ---------------------------------------------------------------------------
__global__ void __launch_bounds__(BLK)
argmin_partial_kernel(const float* __restrict__ pos,
                      const float* __restrict__ mean,
                      unsigned long long* __restrict__ partial,
                      int N) {
    const int b = blockIdx.x / GPB;
    const int g = blockIdx.x % GPB;
    const int t = threadIdx.x;

    float mx[K_PTS], my[K_PTS], mz[K_PTS];
#pragma unroll
    for (int k = 0; k < K_PTS; ++k) {
        mx[k] = mean[k * 3 + 0];
        my[k] = mean[k * 3 + 1];
        mz[k] = mean[k * 3 + 2];
    }

    unsigned long long best[K_PTS];
#pragma unroll
    for (int k = 0; k < K_PTS; ++k) best[k] = ~0ull;

    const float* posb = pos + (size_t)b * N * 3;
    for (int n = g * BLK + t; n < N; n += GPB * BLK) {
        const float px = posb[n * 3 + 0];
        const float py = posb[n * 3 + 1];
        const float pz = posb[n * 3 + 2];
#pragma unroll
        for (int k = 0; k < K_PTS; ++k) {
            const float dx = px - mx[k];
            const float dy = py - my[k];
            const float dz = pz - mz[k];
            const float d2 = dx * dx + dy * dy + dz * dz;
            const unsigned long long p =
                ((unsigned long long)__float_as_uint(d2) << 32) | (unsigned int)n;
            if (p < best[k]) best[k] = p;
        }
    }

    // wave-level reduce (64 lanes), then one LDS step across the 4 waves
#pragma unroll
    for (int k = 0; k < K_PTS; ++k) {
#pragma unroll
        for (int s = 32; s > 0; s >>= 1) {
            const unsigned long long o = __shfl_down(best[k], s, 64);
            if (o < best[k]) best[k] = o;
        }
    }

    __shared__ unsigned long long red[K_PTS][BLK / 64];   // 8 * 4 u64
    const int wave = t >> 6;
    const int lane = t & 63;
    if (lane == 0) {
#pragma unroll
        for (int k = 0; k < K_PTS; ++k) red[k][wave] = best[k];
    }
    __syncthreads();

    if (t < K_PTS) {
        unsigned long long m = red[t][0];
#pragma unroll
        for (int w = 1; w < BLK / 64; ++w)
            if (red[t][w] < m) m = red[t][w];
        partial[((size_t)b * K_PTS + t) * GPB + g] = m;
    }
}

// ---------------------------------------------------------------------------
// Kernel 2: one block per batch. Reduce the GPB partials per k (32-lane
// shuffle groups), dedup the K winning indices (union == clip(sum onehot)),
// then out[b,h] = bias[h] + sum_u x[b,n_u] * W[n_u,h].
// ---------------------------------------------------------------------------
__global__ void __launch_bounds__(HID)
finish_kernel(const float* __restrict__ x,
              const float* __restrict__ weight,   // [N][HID]
              const float* __restrict__ bias,     // [HID]
              const unsigned long long* __restrict__ partial,
              float* __restrict__ out,            // [BATCH][HID]
              int N) {
    const int b = blockIdx.x;
    const int t = threadIdx.x;

    __shared__ int sel[K_PTS];
    __shared__ int nsel;

    // 8 groups of 32 threads; group k reduces its 64 partials
    {
        const int k = t >> 5;          // 0..7
        const int l = t & 31;          // 0..31
        const unsigned long long* pk = partial + ((size_t)b * K_PTS + k) * GPB;
        unsigned long long v = pk[l];
        const unsigned long long v2 = pk[l + 32];
        if (v2 < v) v = v2;
#pragma unroll
        for (int s = 16; s > 0; s >>= 1) {
            const unsigned long long o = __shfl_down(v, s, 32);
            if (o < v) v = o;
        }
        if (l == 0) sel[k] = (int)(v & 0xFFFFFFFFull);
    }
    __syncthreads();

    if (t == 0) {
        int idxs[K_PTS];
#pragma unroll
        for (int k = 0; k < K_PTS; ++k) idxs[k] = sel[k];
        int u = 0;
#pragma unroll
        for (int k = 0; k < K_PTS; ++k) {
            bool dup = false;
#pragma unroll
            for (int j = 0; j < K_PTS; ++j)
                dup |= (j < k) && (idxs[j] == idxs[k]);
            if (!dup) sel[u++] = idxs[k];
        }
        nsel = u;
    }
    __syncthreads();

    float acc = bias[t];
    const int u = nsel;
    for (int i = 0; i < u; ++i) {
        const int n = sel[i];
        acc += x[(size_t)b * N + n] * weight[(size_t)n * HID + t];
    }
    out[b * HID + t] = acc;
}

extern "C" void kernel_launch(void* const* d_in, const int* in_sizes, int n_in,
                              void* d_out, int out_size, void* d_ws, size_t ws_size,
                              hipStream_t stream) {
    const float* x      = (const float*)d_in[0];   // [B, N]
    const float* pos    = (const float*)d_in[1];   // [B, N, 3]
    const float* mean   = (const float*)d_in[2];   // [K, 3]
    const float* weight = (const float*)d_in[3];   // [1, N, H]
    const float* bias   = (const float*)d_in[4];   // [1, H]
    float* out = (float*)d_out;

    const int N = in_sizes[0] / BATCH;

    unsigned long long* partial = (unsigned long long*)d_ws;  // [B][K][GPB]

    argmin_partial_kernel<<<BATCH * GPB, BLK, 0, stream>>>(pos, mean, partial, N);
    finish_kernel<<<BATCH, HID, 0, stream>>>(x, weight, bias, partial, out, N);
}